// Round 3
// baseline (2444.722 us; speedup 1.0000x reference)
//
#include <hip/hip_runtime.h>
#include <stdint.h>

#define HMAP_MASK ((1u << 19) - 1u)

__global__ __launch_bounds__(256) void energy4d_kernel(
    const float4* __restrict__ coords,
    const float4* __restrict__ refc,
    const float2* __restrict__ t0,
    const float2* __restrict__ t1,
    const float2* __restrict__ t2,
    const float2* __restrict__ t3,
    float2* __restrict__ out, int npts)
{
    // Match XLA-f32 semantics bit-for-bit: no fma contraction anywhere in the
    // u/pos/w chain (XLA rounds each HLO op separately).
    #pragma clang fp contract(off)

    int tid = blockIdx.x * blockDim.x + threadIdx.x;
    int point = tid >> 6;
    if (point >= npts) return;
    int sub = tid & 63;
    int table_id = sub >> 4;
    int level = sub & 15;

    float4 c = coords[point];
    float4 r = refc[point];
    float rx = c.x - r.x, ry = c.y - r.y, rz = c.z - r.z, rt = c.w - r.w;

    // _norm: XLA rewrites (v-lo)/(hi-lo) into (v-lo) * (1/(hi-lo)) with the
    // f32-rounded reciprocal (div-by-const -> recip-mul canonicalization).
    const float R180   = 1.0f / 180.0f;    // compile-time f32 reciprocal
    const float R360   = 1.0f / 360.0f;
    const float R20000 = 1.0f / 20000.0f;
    float x = fminf(fmaxf((rx + 90.0f)    * R180,   0.0f), 1.0f);
    float y = fminf(fmaxf((ry + 180.0f)   * R360,   0.0f), 1.0f);
    float z = fminf(fmaxf((rz + 11000.0f) * R20000, 0.0f), 1.0f);
    float t = fminf(fmaxf(rt, 0.0f), 1.0f);           // /1.0 folds away
    float ts = (t * 2.0f - 1.0f) * 0.9f;

    // dim selection per table: t0=(x,y,z) t1=(x,y,ts) t2=(y,z,ts) t3=(x,z,ts)
    float d0 = (table_id == 2) ? y : x;
    float d1 = (table_id <= 1) ? y : z;
    float d2 = (table_id == 0) ? z : ts;
    const float2* tab = (table_id == 0) ? t0
                      : (table_id == 1) ? t1
                      : (table_id == 2) ? t2 : t3;

    // hash_encode: u = clip((d+1)/2, 0, 1); /2 is exact as *0.5
    float u0 = fminf(fmaxf((d0 + 1.0f) * 0.5f, 0.0f), 1.0f);
    float u1 = fminf(fmaxf((d1 + 1.0f) * 0.5f, 0.0f), 1.0f);
    float u2 = fminf(fmaxf((d2 + 1.0f) * 0.5f, 0.0f), 1.0f);

    int res = 32 << level;                 // ceil(32*2^l) exact
    float resm1 = (float)(res - 1);
    float pos0 = u0 * resm1;
    float pos1 = u1 * resm1;
    float pos2 = u2 * resm1;
    int p0 = min(max((int)floorf(pos0), 0), res - 2);
    int p1 = min(max((int)floorf(pos1), 0), res - 2);
    int p2 = min(max((int)floorf(pos2), 0), res - 2);
    float w0 = pos0 - (float)p0;   // contract(off): uses rounded pos
    float w1 = pos1 - (float)p1;
    float w2 = pos2 - (float)p2;

    // level offsets: l0->0 (dense 32^3), l1->32768 (dense 64^3=262144),
    // l>=2 -> 294912 + (l-2)*524288 (hashed)
    int off = (level >= 2) ? (294912 + ((level - 2) << 19)) : (level << 15);
    bool use_hash = (level >= 2);
    const float2* tabo = tab + off;

    float om0 = 1.0f - w0, om1 = 1.0f - w1, om2 = 1.0f - w2;
    float a0 = 0.0f, a1 = 0.0f;
    uint32_t ures = (uint32_t)res;

    #pragma unroll
    for (int ci = 0; ci < 8; ++ci) {
        int cx = ci & 1, cy = (ci >> 1) & 1, cz = (ci >> 2) & 1;
        uint32_t px = (uint32_t)(p0 + cx);
        uint32_t py = (uint32_t)(p1 + cy);
        uint32_t pz = (uint32_t)(p2 + cz);
        uint32_t idx;
        if (use_hash) {
            idx = (px ^ (py * 2654435761u) ^ (pz * 805459861u)) & HMAP_MASK;
        } else {
            idx = px + ures * (py + ures * pz);
        }
        float2 f = tabo[idx];
        float ww = (cx ? w0 : om0) * (cy ? w1 : om1) * (cz ? w2 : om2);
        a0 += f.x * ww;
        a1 += f.y * ww;
    }

    out[(size_t)point * 64 + sub] = make_float2(a0, a1);
}

extern "C" void kernel_launch(void* const* d_in, const int* in_sizes, int n_in,
                              void* d_out, int out_size, void* d_ws, size_t ws_size,
                              hipStream_t stream) {
    const float4* coords = (const float4*)d_in[0];
    const float4* refc   = (const float4*)d_in[1];
    const float2* t0 = (const float2*)d_in[2];
    const float2* t1 = (const float2*)d_in[3];
    const float2* t2 = (const float2*)d_in[4];
    const float2* t3 = (const float2*)d_in[5];
    float2* out = (float2*)d_out;
    int npts = in_sizes[0] / 4;
    long long total = (long long)npts * 64;
    int block = 256;
    int grid = (int)((total + block - 1) / block);
    energy4d_kernel<<<grid, block, 0, stream>>>(coords, refc, t0, t1, t2, t3, out, npts);
}